// Round 9
// baseline (723.200 us; speedup 1.0000x reference)
//
#include <hip/hip_runtime.h>
#include <hip/hip_fp16.h>
#include <math.h>

#define NN 100000
#define NE 1600000
#define NB ((NN + 255) >> 8)   // 391 buckets of 256 nodes
#define CHUNK 8192
#define CAP 8192

typedef __attribute__((ext_vector_type(4))) float floatx4;
typedef __attribute__((ext_vector_type(8))) short shortx8;

// ---------------- bucketed CSR build ----------------

__global__ __launch_bounds__(256)
void coarse_hist(const int* __restrict__ ei, int* __restrict__ bucket_cnt, int E) {
    __shared__ int h[512];
    int t = threadIdx.x;
    for (int i = t; i < 512; i += 256) h[i] = 0;
    __syncthreads();
    int base = blockIdx.x * CHUNK;
    int lim = min(base + CHUNK, E);
    for (int e = base + t; e < lim; e += 256) {
        int d = ei[E + e];
        atomicAdd(&h[d >> 8], 1);
    }
    __syncthreads();
    for (int i = t; i < 512; i += 256)
        if (h[i]) atomicAdd(&bucket_cnt[i], h[i]);
}

__global__ void scan_buckets(const int* __restrict__ bucket_cnt,
                             int* __restrict__ bucket_base,
                             int* __restrict__ bucket_fill) {
    __shared__ int sh[512];
    int t = threadIdx.x;  // 512 threads
    int v = (t < NB) ? bucket_cnt[t] : 0;
    sh[t] = v;
    __syncthreads();
    for (int off = 1; off < 512; off <<= 1) {
        int u = (t >= off) ? sh[t - off] : 0;
        __syncthreads();
        sh[t] += u;
        __syncthreads();
    }
    int ex = (t == 0) ? 0 : sh[t - 1];
    if (t <= NB) bucket_base[t] = ex;
    if (t < NB) bucket_fill[t] = ex;
}

__global__ __launch_bounds__(256)
void coarse_scatter(const int* __restrict__ ei, int* __restrict__ bucket_fill,
                    unsigned long long* __restrict__ pairs, int E) {
    __shared__ int h[512];
    __shared__ int base[512];
    int t = threadIdx.x;
    for (int i = t; i < 512; i += 256) h[i] = 0;
    __syncthreads();
    int cbase = blockIdx.x * CHUNK;
    int lim = min(cbase + CHUNK, E);
    for (int e = cbase + t; e < lim; e += 256) {
        int d = ei[E + e];
        atomicAdd(&h[d >> 8], 1);
    }
    __syncthreads();
    for (int i = t; i < 512; i += 256)
        base[i] = h[i] ? atomicAdd(&bucket_fill[i], h[i]) : 0;
    __syncthreads();
    for (int i = t; i < 512; i += 256) h[i] = 0;
    __syncthreads();
    for (int e = cbase + t; e < lim; e += 256) {
        int s = ei[e];
        int d = ei[E + e];
        int b = d >> 8;
        int r = atomicAdd(&h[b], 1);
        pairs[base[b] + r] =
            ((unsigned long long)(unsigned)d << 32) | (unsigned)s;
    }
}

__global__ __launch_bounds__(256)
void fine_csr(const unsigned long long* __restrict__ pairs,
              const int* __restrict__ bucket_base,
              int* __restrict__ rowptr, int* __restrict__ colid,
              float* __restrict__ dinv, int n) {
    __shared__ int hist[256];
    __shared__ int offs[256];
    __shared__ int rank[256];
    __shared__ int lbuf[CAP];
    int b = blockIdx.x, t = threadIdx.x;
    int beg = bucket_base[b], end = bucket_base[b + 1];
    int cnt = end - beg;
    hist[t] = 0; rank[t] = 0;
    __syncthreads();
    for (int i = t; i < cnt; i += 256) {
        int d = (int)(pairs[beg + i] >> 32);
        atomicAdd(&hist[d & 255], 1);
    }
    __syncthreads();
    int v = hist[t];
    offs[t] = v;
    __syncthreads();
    for (int off = 1; off < 256; off <<= 1) {
        int u = (t >= off) ? offs[t - off] : 0;
        __syncthreads();
        offs[t] += u;
        __syncthreads();
    }
    int ex = (t == 0) ? 0 : offs[t - 1];
    int node = (b << 8) + t;
    if (node < n) {
        rowptr[node] = beg + ex;
        dinv[node] = rsqrtf((float)v + 1.0f);
    } else if (node == n) {
        rowptr[n] = beg + ex;
    }
    __syncthreads();
    offs[t] = ex;
    __syncthreads();
    for (int i = t; i < cnt; i += 256) {
        unsigned long long p = pairs[beg + i];
        int d = (int)(p >> 32) & 255;
        int s = (int)(p & 0xffffffffu);
        int r = atomicAdd(&rank[d], 1);
        lbuf[offs[d] + r] = s;
    }
    __syncthreads();
    for (int i = t; i < cnt; i += 256) colid[beg + i] = lbuf[i];
}

// ---------------- weight prep: W[K][OUT] fp32 -> swizzled bf16 hi/lo fragments ----

__device__ __forceinline__ void wsplit_one(const float* __restrict__ W,
                                           unsigned short* __restrict__ Wsw,
                                           int i, int K, int OUT) {
    int k = i / OUT, o = i % OUT;
    float w = W[i];
    unsigned u = __float_as_uint(w);
    float r = w - __uint_as_float(u & 0xFFFF0000u);
    int NT = OUT >> 4;
    int ktc = k >> 5, q = (k >> 3) & 3, j = k & 7;
    int nt = o >> 4, mm = o & 15;
    int lane = (q << 4) | mm;
    size_t base = ((((size_t)(ktc * NT + nt) * 2) * 64 + lane) << 3) + j;
    Wsw[base] = (unsigned short)(u >> 16);
    Wsw[base + 512] = (unsigned short)(__float_as_uint(r) >> 16);  // h=1: +64*8
}

__global__ __launch_bounds__(256)
void wsplit_all(const float* __restrict__ W0, unsigned short* __restrict__ O0,
                const float* __restrict__ W1, unsigned short* __restrict__ O1,
                const float* __restrict__ W2, unsigned short* __restrict__ O2,
                const float* __restrict__ W3, unsigned short* __restrict__ O3,
                const float* __restrict__ W4, unsigned short* __restrict__ O4,
                const float* __restrict__ W5, unsigned short* __restrict__ O5) {
    int i = blockIdx.x * 256 + threadIdx.x;
    if (i < 20480) { wsplit_one(W0, O0, i, 160, 128); return; }
    i -= 20480;
    if (i < 16384) { wsplit_one(W1, O1, i, 128, 128); return; }
    i -= 16384;
    if (i < 8192)  { wsplit_one(W2, O2, i, 128, 64);  return; }
    i -= 8192;
    if (i < 12288) { wsplit_one(W3, O3, i, 96, 128);  return; }
    i -= 12288;
    if (i < 16384) { wsplit_one(W4, O4, i, 128, 128); return; }
    i -= 16384;
    if (i < 16384) { wsplit_one(W5, O5, i, 128, 128); }
}

// ---------------- standalone MFMA GEMM (layer e1 only) ------------------------
// r7 v3: 512 thr, 8 waves x 2 row-tiles (proven). fp32 inputs + split8.

__device__ __forceinline__ void split8(const float* v, shortx8& hi, shortx8& lo) {
#pragma unroll
    for (int i = 0; i < 8; i++) {
        unsigned u = __float_as_uint(v[i]);
        float r = v[i] - __uint_as_float(u & 0xFFFF0000u);
        hi[i] = (short)(u >> 16);
        lo[i] = (short)(__float_as_uint(r) >> 16);
    }
}

template <int OUT, int K, int K1>
__global__ __launch_bounds__(512, 4)
void gemm_mfma(const float* __restrict__ X1, const float* __restrict__ X2,
               const unsigned short* __restrict__ Wsw,
               const float* __restrict__ dinv,
               __half* __restrict__ Y, int ntiles) {
    constexpr int NT = OUT / 16;
    constexpr int NKTC = K / 32;
    constexpr int K2 = K - K1;
    constexpr int PERC = OUT * 128;
    constexpr int CSZ = (65536 / PERC < NKTC) ? (65536 / PERC) : NKTC;
    __shared__ __align__(16) unsigned short lds[CSZ * PERC / 2];

    const int t = threadIdx.x;
    const int wave = t >> 6, lane = t & 63;
    const int m = lane & 15, q = lane >> 4;
    const int tile0 = blockIdx.x * 16 + wave * 2;
    const int tile1 = tile0 + 1;
    const bool act0 = tile0 < ntiles;
    const bool act1 = tile1 < ntiles;
    const int r0 = act0 ? tile0 * 16 + m : 0;
    const int r1 = act1 ? tile1 * 16 + m : 0;
    const float* ap1a = X1 + (size_t)r0 * K1 + q * 8;
    const float* ap1b = X1 + (size_t)r1 * K1 + q * 8;
    const float* ap2a = (K2 > 0) ? (X2 + (size_t)r0 * K2 + q * 8) : X1;
    const float* ap2b = (K2 > 0) ? (X2 + (size_t)r1 * K2 + q * 8) : X1;

    floatx4 acc0[NT], acc1[NT];
#pragma unroll
    for (int nt = 0; nt < NT; nt++) {
        acc0[nt] = (floatx4){0.f, 0.f, 0.f, 0.f};
        acc1[nt] = (floatx4){0.f, 0.f, 0.f, 0.f};
    }

#pragma unroll
    for (int c0 = 0; c0 < NKTC; c0 += CSZ) {
        const int cl = (NKTC - c0 < CSZ) ? (NKTC - c0) : CSZ;
        if (c0 != 0) __syncthreads();
        {
            const float4* gs = (const float4*)Wsw + (size_t)c0 * (PERC / 16);
            float4* ld = (float4*)lds;
            int tot = cl * (PERC / 16);
            for (int i = t; i < tot; i += 512) ld[i] = gs[i];
        }
        __syncthreads();
#pragma unroll
        for (int ktc = 0; ktc < cl; ktc++) {
            const int kg = (c0 + ktc) * 32;
            const float* pa = (kg < K1) ? (ap1a + kg) : (ap2a + (kg - K1));
            const float* pb = (kg < K1) ? (ap1b + kg) : (ap2b + (kg - K1));
            float av0[8], av1[8];
            *(float4*)&av0[0] = *(const float4*)(pa);
            *(float4*)&av0[4] = *(const float4*)(pa + 4);
            *(float4*)&av1[0] = *(const float4*)(pb);
            *(float4*)&av1[4] = *(const float4*)(pb + 4);
            shortx8 ahi0, alo0, ahi1, alo1;
            split8(av0, ahi0, alo0);
            split8(av1, ahi1, alo1);
#pragma unroll
            for (int nt = 0; nt < NT; nt++) {
                const unsigned short* fb =
                    lds + ((((ktc * NT + nt) * 2) * 64 + lane) << 3);
                shortx8 bhi = *(const shortx8*)fb;
                shortx8 blo = *(const shortx8*)(fb + 512);
                acc0[nt] = __builtin_amdgcn_mfma_f32_16x16x32_bf16(ahi0, bhi, acc0[nt], 0, 0, 0);
                acc1[nt] = __builtin_amdgcn_mfma_f32_16x16x32_bf16(ahi1, bhi, acc1[nt], 0, 0, 0);
                acc0[nt] = __builtin_amdgcn_mfma_f32_16x16x32_bf16(ahi0, blo, acc0[nt], 0, 0, 0);
                acc1[nt] = __builtin_amdgcn_mfma_f32_16x16x32_bf16(ahi1, blo, acc1[nt], 0, 0, 0);
                acc0[nt] = __builtin_amdgcn_mfma_f32_16x16x32_bf16(alo0, bhi, acc0[nt], 0, 0, 0);
                acc1[nt] = __builtin_amdgcn_mfma_f32_16x16x32_bf16(alo1, bhi, acc1[nt], 0, 0, 0);
            }
        }
    }

    if (act0) {
        float di[4];
#pragma unroll
        for (int r = 0; r < 4; r++) di[r] = dinv[tile0 * 16 + q * 4 + r];
#pragma unroll
        for (int nt = 0; nt < NT; nt++)
#pragma unroll
            for (int r = 0; r < 4; r++) {
                int orow = tile0 * 16 + q * 4 + r;
                Y[(size_t)orow * OUT + nt * 16 + m] =
                    __float2half_rn(acc0[nt][r] * di[r]);
            }
    }
    if (act1) {
        float di[4];
#pragma unroll
        for (int r = 0; r < 4; r++) di[r] = dinv[tile1 * 16 + q * 4 + r];
#pragma unroll
        for (int nt = 0; nt < NT; nt++)
#pragma unroll
            for (int r = 0; r < 4; r++) {
                int orow = tile1 * 16 + q * 4 + r;
                Y[(size_t)orow * OUT + nt * 16 + m] =
                    __float2half_rn(acc1[nt][r] * di[r]);
            }
    }
}

// ---------------- FUSED prop(i) + GEMM(i+1), v2: 32 nodes/block ---------------
// r8 analysis: fused = 92 us vs 71 us pure gather; the +21 is W-fragment L2
// request flood (64KB/16-row block = 6.4M extra 64B segments/dispatch on the
// request-rate-limited path). v2: block = 32 nodes (2 row-tiles), 4 waves.
// Phase 1: wave gathers 8 nodes (verbatim prop_row loop). Phase 2: wave owns
// col-tiles {w, w+4}, computes BOTH row-tiles per W fragment load -> W request
// per row halved (3.2M segs), ds_read per MFMA halved. LDS 16KB (hi/lo, 32
// rows x 256B stride, same verified swizzle as r8; lo at +8KB).

template <int INW, int OUT, bool CC, bool TANH>
__global__ __launch_bounds__(256)
void fused_pg(const __half2* __restrict__ hin, const float* __restrict__ dinv,
              const int* __restrict__ rowptr, const int* __restrict__ colid,
              const float* __restrict__ biasIn, const float* __restrict__ cond,
              const unsigned short* __restrict__ Wsw,
              __half* __restrict__ hout, int n) {
    constexpr int KG = CC ? INW + 32 : INW;   // GEMM K
    constexpr int NT = OUT / 16;
    constexpr int NPW = NT / 4;               // col-tiles per wave (2 or 1)
    constexpr int NKTC = KG / 32;
    constexpr int LPR = INW / 4;              // lanes per row in gather
    constexpr int G = 64 / LPR;               // edge groups
    constexpr int RS2 = INW / 4;              // float2 per row

    __shared__ __align__(16) unsigned char xlds[16384];  // hi[32][128] + lo[32][128] bf16

    const int t = threadIdx.x;
    const int wave = t >> 6, lane = t & 63;
    const int blk = blockIdx.x;
    const int g = lane / LPR, fq = lane % LPR;
    const float2* __restrict__ b2 = (const float2*)hin;

    // ---- phase 1: gather 8 nodes per wave ----
    for (int nd = 0; nd < 8; nd++) {
        const int r = wave * 8 + nd;          // local row 0..31
        int node = blk * 32 + r;
        int beg = rowptr[node], end = rowptr[node + 1];
        float ax = 0.f, ay = 0.f, az = 0.f, aw = 0.f;
        int e = beg;
        for (; e + 8 * G <= end; e += 8 * G) {
            int s[8];
#pragma unroll
            for (int j = 0; j < 8; j++) s[j] = colid[e + j * G + g];
            float2 v[8];
#pragma unroll
            for (int j = 0; j < 8; j++) v[j] = b2[(size_t)s[j] * RS2 + fq];
#pragma unroll
            for (int j = 0; j < 8; j++) {
                float2 f0 = __half22float2(*(const __half2*)&v[j].x);
                float2 f1 = __half22float2(*(const __half2*)&v[j].y);
                ax += f0.x; ay += f0.y; az += f1.x; aw += f1.y;
            }
        }
        if (e + 4 * G <= end) {
            int s[4];
#pragma unroll
            for (int j = 0; j < 4; j++) s[j] = colid[e + j * G + g];
            float2 v[4];
#pragma unroll
            for (int j = 0; j < 4; j++) v[j] = b2[(size_t)s[j] * RS2 + fq];
#pragma unroll
            for (int j = 0; j < 4; j++) {
                float2 f0 = __half22float2(*(const __half2*)&v[j].x);
                float2 f1 = __half22float2(*(const __half2*)&v[j].y);
                ax += f0.x; ay += f0.y; az += f1.x; aw += f1.y;
            }
            e += 4 * G;
        }
        for (; e + G <= end; e += G) {
            int s = colid[e + g];
            float2 v = b2[(size_t)s * RS2 + fq];
            float2 f0 = __half22float2(*(const __half2*)&v.x);
            float2 f1 = __half22float2(*(const __half2*)&v.y);
            ax += f0.x; ay += f0.y; az += f1.x; aw += f1.y;
        }
        if (e + g < end) {
            int s = colid[e + g];
            float2 v = b2[(size_t)s * RS2 + fq];
            float2 f0 = __half22float2(*(const __half2*)&v.x);
            float2 f1 = __half22float2(*(const __half2*)&v.y);
            ax += f0.x; ay += f0.y; az += f1.x; aw += f1.y;
        }
        if constexpr (G >= 2) {
            ax += __shfl_xor(ax, LPR); ay += __shfl_xor(ay, LPR);
            az += __shfl_xor(az, LPR); aw += __shfl_xor(aw, LPR);
        }
        if constexpr (G == 4) {
            ax += __shfl_xor(ax, 2 * LPR); ay += __shfl_xor(ay, 2 * LPR);
            az += __shfl_xor(az, 2 * LPR); aw += __shfl_xor(aw, 2 * LPR);
        }
        if (g == 0) {
            float2 sv = b2[(size_t)node * RS2 + fq];
            float2 f0 = __half22float2(*(const __half2*)&sv.x);
            float2 f1 = __half22float2(*(const __half2*)&sv.y);
            ax += f0.x; ay += f0.y; az += f1.x; aw += f1.y;
            float di = dinv[node];
            float4 bb = *(const float4*)(biasIn + fq * 4);
            float o0 = di * ax + bb.x;
            float o1 = di * ay + bb.y;
            float o2 = di * az + bb.z;
            float o3 = di * aw + bb.w;
            if (TANH) { o0 = tanhf(o0); o1 = tanhf(o1); o2 = tanhf(o2); o3 = tanhf(o3); }
            float o[4] = {o0, o1, o2, o3};
            unsigned short hi[4], lo[4];
#pragma unroll
            for (int i = 0; i < 4; i++) {
                unsigned u = __float_as_uint(o[i]);
                float rr = o[i] - __uint_as_float(u & 0xFFFF0000u);
                hi[i] = (unsigned short)(u >> 16);
                lo[i] = (unsigned short)(__float_as_uint(rr) >> 16);
            }
            int off = (r * 256 + fq * 8) ^ ((r & 7) << 4);
            *(uint2*)(xlds + off) = *(const uint2*)hi;
            *(uint2*)(xlds + 8192 + off) = *(const uint2*)lo;
        }
        if constexpr (CC) {
            if (g == 1 && fq < 8) {
                float4 cv = ((const float4*)cond)[(size_t)node * 8 + fq];
                float c[4] = {cv.x, cv.y, cv.z, cv.w};
                unsigned short hi[4], lo[4];
#pragma unroll
                for (int i = 0; i < 4; i++) {
                    unsigned u = __float_as_uint(c[i]);
                    float rr = c[i] - __uint_as_float(u & 0xFFFF0000u);
                    hi[i] = (unsigned short)(u >> 16);
                    lo[i] = (unsigned short)(__float_as_uint(rr) >> 16);
                }
                int off = (r * 256 + 128 + fq * 8) ^ ((r & 7) << 4);
                *(uint2*)(xlds + off) = *(const uint2*)hi;
                *(uint2*)(xlds + 8192 + off) = *(const uint2*)lo;
            }
        }
    }
    __syncthreads();

    // ---- phase 2: GEMM 32 x KG @ KG x OUT; wave covers nts {w, w+4}, both row-tiles ----
    const int m = lane & 15, q = lane >> 4;
    floatx4 acc[NPW][2];
#pragma unroll
    for (int j = 0; j < NPW; j++) {
        acc[j][0] = (floatx4){0.f, 0.f, 0.f, 0.f};
        acc[j][1] = (floatx4){0.f, 0.f, 0.f, 0.f};
    }

#pragma unroll
    for (int kc = 0; kc < NKTC; kc++) {
        int rd0 = (m * 256 + kc * 64 + q * 16) ^ ((m & 7) << 4);
        int m2 = m + 16;
        int rd1 = (m2 * 256 + kc * 64 + q * 16) ^ ((m2 & 7) << 4);
        shortx8 ahi0 = *(const shortx8*)(xlds + rd0);
        shortx8 alo0 = *(const shortx8*)(xlds + 8192 + rd0);
        shortx8 ahi1 = *(const shortx8*)(xlds + rd1);
        shortx8 alo1 = *(const shortx8*)(xlds + 8192 + rd1);
#pragma unroll
        for (int j = 0; j < NPW; j++) {
            int nt = wave + j * 4;
            const unsigned short* wp =
                Wsw + ((((size_t)(kc * NT + nt) * 2) * 64 + lane) << 3);
            shortx8 whi = *(const shortx8*)wp;
            shortx8 wlo = *(const shortx8*)(wp + 512);
            acc[j][0] = __builtin_amdgcn_mfma_f32_16x16x32_bf16(ahi0, whi, acc[j][0], 0, 0, 0);
            acc[j][1] = __builtin_amdgcn_mfma_f32_16x16x32_bf16(ahi1, whi, acc[j][1], 0, 0, 0);
            acc[j][0] = __builtin_amdgcn_mfma_f32_16x16x32_bf16(ahi0, wlo, acc[j][0], 0, 0, 0);
            acc[j][1] = __builtin_amdgcn_mfma_f32_16x16x32_bf16(ahi1, wlo, acc[j][1], 0, 0, 0);
            acc[j][0] = __builtin_amdgcn_mfma_f32_16x16x32_bf16(alo0, whi, acc[j][0], 0, 0, 0);
            acc[j][1] = __builtin_amdgcn_mfma_f32_16x16x32_bf16(alo1, whi, acc[j][1], 0, 0, 0);
        }
    }

#pragma unroll
    for (int rt = 0; rt < 2; rt++) {
        float di[4];
#pragma unroll
        for (int rr = 0; rr < 4; rr++)
            di[rr] = dinv[blk * 32 + rt * 16 + q * 4 + rr];
#pragma unroll
        for (int j = 0; j < NPW; j++) {
            int nt = wave + j * 4;
#pragma unroll
            for (int rr = 0; rr < 4; rr++) {
                int orow = blk * 32 + rt * 16 + q * 4 + rr;
                hout[(size_t)orow * OUT + nt * 16 + m] =
                    __float2half_rn(acc[j][rt][rr] * di[rr]);
            }
        }
    }
}

// ---------------- standalone propagation (layer d3 tail) ----------------------
// PROVEN config (rounds 3/6/7: 70.5-71.2 us, 192 MB fetch = compulsory floor).

template <int OUT, bool TANH>
__global__ __launch_bounds__(256)
void prop_row(const __half2* __restrict__ hs, const float* __restrict__ dinv,
              const int* __restrict__ rowptr, const int* __restrict__ colid,
              const float* __restrict__ bias, float* __restrict__ out,
              int ldo, int n) {
    constexpr int LPR = OUT / 4;
    constexpr int G = 64 / LPR;
    constexpr int RS2 = OUT / 4;

    int wave = threadIdx.x >> 6, lane = threadIdx.x & 63;
    int node = blockIdx.x * 4 + wave;
    if (node >= n) return;
    int g = lane / LPR, fq = lane % LPR;
    int beg = rowptr[node], end = rowptr[node + 1];
    const float2* __restrict__ b2 = (const float2*)hs;

    float ax = 0.f, ay = 0.f, az = 0.f, aw = 0.f;
    int e = beg;
    for (; e + 8 * G <= end; e += 8 * G) {
        int s[8];
#pragma unroll
        for (int j = 0; j < 8; j++) s[j] = colid[e + j * G + g];
        float2 v[8];
#pragma unroll
        for (int j = 0; j < 8; j++) v[j] = b2[(size_t)s[j] * RS2 + fq];
#pragma unroll
        for (int j = 0; j < 8; j++) {
            float2 f0 = __half22float2(*(const __half2*)&v[j].x);
            float2 f1 = __half22float2(*(const __half2*)&v[j].y);
            ax += f0.x; ay += f0.y; az += f1.x; aw += f1.y;
        }
    }
    if (e + 4 * G <= end) {
        int s[4];
#pragma unroll
        for (int j = 0; j < 4; j++) s[j] = colid[e + j * G + g];
        float2 v[4];
#pragma unroll
        for (int j = 0; j < 4; j++) v[j] = b2[(size_t)s[j] * RS2 + fq];
#pragma unroll
        for (int j = 0; j < 4; j++) {
            float2 f0 = __half22float2(*(const __half2*)&v[j].x);
            float2 f1 = __half22float2(*(const __half2*)&v[j].y);
            ax += f0.x; ay += f0.y; az += f1.x; aw += f1.y;
        }
        e += 4 * G;
    }
    for (; e + G <= end; e += G) {
        int s = colid[e + g];
        float2 v = b2[(size_t)s * RS2 + fq];
        float2 f0 = __half22float2(*(const __half2*)&v.x);
        float2 f1 = __half22float2(*(const __half2*)&v.y);
        ax += f0.x; ay += f0.y; az += f1.x; aw += f1.y;
    }
    if (e + g < end) {
        int s = colid[e + g];
        float2 v = b2[(size_t)s * RS2 + fq];
        float2 f0 = __half22float2(*(const __half2*)&v.x);
        float2 f1 = __half22float2(*(const __half2*)&v.y);
        ax += f0.x; ay += f0.y; az += f1.x; aw += f1.y;
    }

    if constexpr (G >= 2) {
        ax += __shfl_xor(ax, LPR); ay += __shfl_xor(ay, LPR);
        az += __shfl_xor(az, LPR); aw += __shfl_xor(aw, LPR);
    }
    if constexpr (G == 4) {
        ax += __shfl_xor(ax, 2 * LPR); ay += __shfl_xor(ay, 2 * LPR);
        az += __shfl_xor(az, 2 * LPR); aw += __shfl_xor(aw, 2 * LPR);
    }

    if (g == 0) {
        float2 sv = b2[(size_t)node * RS2 + fq];
        float2 f0 = __half22float2(*(const __half2*)&sv.x);
        float2 f1 = __half22float2(*(const __half2*)&sv.y);
        ax += f0.x; ay += f0.y; az += f1.x; aw += f1.y;
        float di = dinv[node];
        float4 bb = *(const float4*)(bias + fq * 4);
        float ox = di * ax + bb.x;
        float oy = di * ay + bb.y;
        float oz = di * az + bb.z;
        float ow = di * aw + bb.w;
        if (TANH) { ox = tanhf(ox); oy = tanhf(oy); oz = tanhf(oz); ow = tanhf(ow); }
        *(float4*)(out + (size_t)node * ldo + fq * 4) = make_float4(ox, oy, oz, ow);
    }
}

// ---------------- launch ----------------

extern "C" void kernel_launch(void* const* d_in, const int* in_sizes, int n_in,
                              void* d_out, int out_size, void* d_ws, size_t ws_size,
                              hipStream_t stream) {
    const int n = NN, E = NE;
    const float* feature   = (const float*)d_in[0];
    const float* condition = (const float*)d_in[1];
    const int*   ei        = (const int*)d_in[2];
    const float* W_e1 = (const float*)d_in[3];  const float* b_e1 = (const float*)d_in[4];
    const float* W_e2 = (const float*)d_in[5];  const float* b_e2 = (const float*)d_in[6];
    const float* W_e3 = (const float*)d_in[7];  const float* b_e3 = (const float*)d_in[8];
    const float* W_d1 = (const float*)d_in[9];  const float* b_d1 = (const float*)d_in[10];
    const float* W_d2 = (const float*)d_in[11]; const float* b_d2 = (const float*)d_in[12];
    const float* W_d3 = (const float*)d_in[13]; const float* b_d3 = (const float*)d_in[14];
    float* out = (float*)d_out;

    float*  A    = (float*)d_ws;                    // n*160 floats (H16b lives here)
    __half* H16a = (__half*)(A + (size_t)n * 160);  // n*128 halves
    __half* H16b = (__half*)A;                      // n*128 halves (reuses A slot)
    float*  dinv = (float*)(H16a + (size_t)n * 128); // n
    int* rowptr  = (int*)(dinv + n);                // n+1
    int* colid   = rowptr + n + 1;                  // E
    uintptr_t pp = (uintptr_t)(colid + E);
    pp = (pp + 15) & ~(uintptr_t)15;
    unsigned long long* pairs = (unsigned long long*)pp;  // E
    int* bucket_cnt  = (int*)(pairs + E);           // 512
    int* bucket_base = bucket_cnt + 512;            // 512
    int* bucket_fill = bucket_base + 512;           // 512
    uintptr_t wp = (uintptr_t)(bucket_fill + 512);
    wp = (wp + 15) & ~(uintptr_t)15;
    unsigned short* wt = (unsigned short*)wp;
    unsigned short* e1w = wt;              unsigned short* e2w = e1w + 160 * 128 * 2;
    unsigned short* e3w = e2w + 128*128*2; unsigned short* d1w = e3w + 128 * 64 * 2;
    unsigned short* d2w = d1w + 96*128*2;  unsigned short* d3w = d2w + 128 * 128 * 2;

    hipMemsetAsync(bucket_cnt, 0, 512 * sizeof(int), stream);

    int nbc = (E + CHUNK - 1) / CHUNK;
    coarse_hist<<<nbc, 256, 0, stream>>>(ei, bucket_cnt, E);
    scan_buckets<<<1, 512, 0, stream>>>(bucket_cnt, bucket_base, bucket_fill);
    coarse_scatter<<<nbc, 256, 0, stream>>>(ei, bucket_fill, pairs, E);
    fine_csr<<<NB, 256, 0, stream>>>(pairs, bucket_base, rowptr, colid, dinv, n);

    wsplit_all<<<(90112 + 255) / 256, 256, 0, stream>>>(
        W_e1, e1w, W_e2, e2w, W_e3, e3w, W_d1, d1w, W_d2, d2w, W_d3, d3w);

    const int ntiles = n / 16;          // 6250 exactly
    const int gb = (ntiles + 15) / 16;  // 391 blocks for standalone e1 GEMM
    const int fb = n / 32;              // 3125 fused blocks (32 nodes each)
    const int pb = (n + 3) / 4;         // 25000 blocks for tail prop

    // head: e1 GEMM (feature+condition fp32 -> H16a)
    gemm_mfma<128, 160, 128><<<gb, 512, 0, stream>>>(feature, condition, e1w, dinv, H16a, ntiles);
    // fused prop(e1)+gemm(e2): H16a -> H16b
    fused_pg<128, 128, false, true><<<fb, 256, 0, stream>>>(
        (const __half2*)H16a, dinv, rowptr, colid, b_e1, nullptr, e2w, H16b, n);
    // fused prop(e2)+gemm(e3): H16b -> H16a (n x 64)
    fused_pg<128, 64, false, true><<<fb, 256, 0, stream>>>(
        (const __half2*)H16b, dinv, rowptr, colid, b_e2, nullptr, e3w, H16a, n);
    // fused prop(e3, no tanh)+concat(cond)+gemm(d1): H16a(64) -> H16b
    fused_pg<64, 128, true, false><<<fb, 256, 0, stream>>>(
        (const __half2*)H16a, dinv, rowptr, colid, b_e3, condition, d1w, H16b, n);
    // fused prop(d1)+gemm(d2): H16b -> H16a
    fused_pg<128, 128, false, true><<<fb, 256, 0, stream>>>(
        (const __half2*)H16b, dinv, rowptr, colid, b_d1, nullptr, d2w, H16a, n);
    // fused prop(d2)+gemm(d3): H16a -> H16b
    fused_pg<128, 128, false, true><<<fb, 256, 0, stream>>>(
        (const __half2*)H16a, dinv, rowptr, colid, b_d2, nullptr, d3w, H16b, n);
    // tail: prop(d3) -> out
    prop_row<128, false><<<pb, 256, 0, stream>>>(
        (const __half2*)H16b, dinv, rowptr, colid, b_d3, out, 128, n);
}